// Round 2
// baseline (733.015 us; speedup 1.0000x reference)
//
#include <hip/hip_runtime.h>
#include <math.h>

#define AN 120000
#define NB 8
#define NC 80
#define MAXDET 100

typedef unsigned long long u64;
typedef unsigned int u32;

// identity pass-through that blocks FMA contraction / reassociation across it
__device__ __forceinline__ float opaquef(float x) { asm volatile("" : "+v"(x)); return x; }

// ---------------------------------------------------------------------------
// ctrl layout (u32 words at start of d_ws), zeroed by score_kernel every call:
//   [0..15]  prefix[8]  (u64[8])   radix-select running prefix per image
//   [16..23] need[8]               remaining count within prefix
//   [24..55] done[4][8]            tail-block counters per (level,image)
//   [56..63] gcnt[8]               compaction counters
//   [256..]  hist[4][8][4096] u32  per-level per-image histograms
#define CTRL_WORDS 256
#define HIST_WORDS (4 * 8 * 4096)
#define ZWORDS (CTRL_WORDS + HIST_WORDS)   // 131328 = 513 * 256

// ---------------------------------------------------------------------------
// Phase A: per-anchor max/argmax over 80 classes -> unique 48-bit sort key.
// key = (float_bits(score) << 17) | (131071 - anchor)
// Also zero-inits the ctrl+hist region (re-poisoned to 0xAA before each call).
// ---------------------------------------------------------------------------
__global__ __launch_bounds__(256) void score_kernel(const float* __restrict__ cls,
                                                    u64* __restrict__ keys,
                                                    u32* __restrict__ ctrl) {
    if (blockIdx.x < 513) {
        ctrl[blockIdx.x * 256 + threadIdx.x] = 0;   // 513*256 == ZWORDS exactly
    }
    __shared__ float buf[4][32 * 81];
    const int tid = threadIdx.x;
    const int wave = tid >> 6, lane = tid & 63;
    const long long blockbase = (long long)blockIdx.x * 256;

    for (int h = 0; h < 2; ++h) {
        const long long abase = blockbase + wave * 64 + h * 32;
        const float4* src = (const float4*)(cls + abase * NC);
        float* Bf = buf[wave];
#pragma unroll
        for (int it = 0; it < 10; ++it) {
            int f = lane + it * 64;           // float4 index within 32x80 tile
            float4 v = src[f];                // fully coalesced
            int anch = f / 20, pos = (f % 20) * 4;
            float* dst = Bf + anch * 81 + pos;
            dst[0] = v.x; dst[1] = v.y; dst[2] = v.z; dst[3] = v.w;
        }
        __syncthreads();
        int anch = lane >> 1, half = lane & 1;   // 2 lanes per anchor (stride-81: 2-way max, free)
        const float* row = Bf + anch * 81 + half * 40;
        float best = -1.0f; int bi = 0;
#pragma unroll
        for (int i = 0; i < 40; ++i) {
            float v = row[i];
            if (v > best) { best = v; bi = i; }   // strict > keeps first occurrence
        }
        bi += half * 40;
        float ov = __shfl_xor(best, 1);
        int   oi = __shfl_xor(bi, 1);
        if (ov > best || (ov == best && oi < bi)) { best = ov; }
        if (half == 0) {
            int aglob = (int)(abase + anch);
            int a = aglob % AN;
            keys[aglob] = ((u64)__float_as_uint(best) << 17) | (u64)(131071 - a);
        }
        __syncthreads();
    }
}

// ---------------------------------------------------------------------------
// Phase B: distributed exact radix select, level L of 4 (12-bit digits over the
// 48-bit key). 60 blocks per image build LDS histograms and flush non-zero bins
// to global; the per-image tail block picks the digit (suffix scan) and updates
// prefix/need. After L=3, prefix[img] == exact 1000th-largest key.
// ---------------------------------------------------------------------------
template <int L>
__global__ __launch_bounds__(256) void hist_kernel(const u64* __restrict__ keys,
                                                   u32* __restrict__ ctrl) {
    const int img = blockIdx.x / 60, chunk = blockIdx.x % 60;
    const int tid = threadIdx.x;
    u64* prefixp = (u64*)ctrl;
    u32* gh = ctrl + CTRL_WORDS + (L * 8 + img) * 4096;
    const u64* k = keys + (size_t)img * AN + chunk * 2000;

    __shared__ u32 h[4096];
    __shared__ u32 ss[256];
    __shared__ int s_last;
    for (int d = tid; d < 4096; d += 256) h[d] = 0;
    u64 pref = (L > 0) ? prefixp[img] : 0;   // written by previous launch
    __syncthreads();

    constexpr int shift = 36 - 12 * L;
    for (int i = tid; i < 2000; i += 256) {
        u64 K = k[i];
        if ((K >> (shift + 12)) == pref)
            atomicAdd(&h[(u32)(K >> shift) & 4095], 1u);
    }
    __syncthreads();
    for (int d = tid; d < 4096; d += 256)
        if (h[d]) atomicAdd(&gh[d], h[d]);
    __threadfence();
    __syncthreads();
    if (tid == 0) {
        u32 old = atomicAdd(&ctrl[24 + L * 8 + img], 1u);
        s_last = (old == 59u);
    }
    __syncthreads();
    if (!s_last) return;

    // ---- tail block: pick digit for this image ----
    const u32 need = (L == 0) ? 1000u : ctrl[16 + img];
    u32 b[16]; u32 S = 0;
#pragma unroll
    for (int j = 0; j < 16; ++j) {
        b[j] = __hip_atomic_load(&gh[tid * 16 + j], __ATOMIC_RELAXED, __HIP_MEMORY_SCOPE_AGENT);
        S += b[j];
    }
    ss[tid] = S;
    __syncthreads();
    for (int off = 1; off < 256; off <<= 1) {          // suffix scan across threads
        u32 v = (tid + off < 256) ? ss[tid + off] : 0;
        __syncthreads();
        ss[tid] += v;
        __syncthreads();
    }
    u32 run = ss[tid] - S;                              // count of digits in threads > tid
    for (int j = 15; j >= 0; --j) {                     // high digit -> low within thread
        u32 cge = run + b[j];
        if (cge >= need && run < need) {                // unique (tid,j) satisfies this
            ctrl[16 + img] = need - run;
            prefixp[img] = (pref << 12) | (u64)(tid * 16 + j);
        }
        run = cge;
    }
}

// ---------------------------------------------------------------------------
// Phase C: compact — collect the exactly-1000 keys >= T per image (unsorted).
// ---------------------------------------------------------------------------
__global__ __launch_bounds__(256) void compact_kernel(const u64* __restrict__ keys,
                                                      u32* __restrict__ ctrl,
                                                      u64* __restrict__ topk) {
    const int img = blockIdx.x / 60, chunk = blockIdx.x % 60;
    const u64 T = ((const u64*)ctrl)[img];
    const u64* k = keys + (size_t)img * AN + chunk * 2000;
    for (int i = threadIdx.x; i < 2000; i += 256) {
        u64 K = k[i];
        if (K >= T) {
            u32 p = atomicAdd(&ctrl[56 + img], 1u);
            if (p < 1024) topk[img * 1024 + p] = K;
        }
    }
}

// ---------------------------------------------------------------------------
// Phase D: per-image bitonic sort (descending) of the 1000 keys + decode.
// Class argmax is recomputed from cls for just the selected anchors.
// ---------------------------------------------------------------------------
__global__ __launch_bounds__(1024) void sortdecode_kernel(const u64* __restrict__ topk,
                                                          const u32* __restrict__ ctrl,
                                                          const float* __restrict__ cls,
                                                          const float* __restrict__ reg,
                                                          const float* __restrict__ anch,
                                                          float* __restrict__ tsc,
                                                          int* __restrict__ tcl,
                                                          float* __restrict__ tbox) {
    const int img = blockIdx.x, tid = threadIdx.x;
    __shared__ u64 st[1024];
    const u32 cnt = ctrl[56 + img];   // == 1000 (T exact, keys unique)
    st[tid] = (tid < (int)cnt) ? ~topk[img * 1024 + tid] : ~0ull;
    __syncthreads();
    for (int kk = 2; kk <= 1024; kk <<= 1) {
        for (int j = kk >> 1; j > 0; j >>= 1) {
            int ixj = tid ^ j;
            if (ixj > tid) {
                u64 a = st[tid], bb = st[ixj];
                bool asc = ((tid & kk) == 0);
                if ((a > bb) == asc) { st[tid] = bb; st[ixj] = a; }
            }
            __syncthreads();
        }
    }
    if (tid >= 1000 || tid >= (int)cnt) return;
    u64 K = ~st[tid];
    u32 sb = (u32)(K >> 17);
    int idx = 131071 - (int)(K & 0x1FFFF);
    float score = __uint_as_float(sb);
    size_t gi = (size_t)img * AN + idx;

    // class argmax (first occurrence), only for the 8000 selected anchors
    const float* crow = cls + gi * NC;
    float cb = -1.0f; int ci = 0;
    for (int c = 0; c < NC; ++c) {
        float v = crow[c];
        if (v > cb) { cb = v; ci = c; }
    }

    float4 r = ((const float4*)reg)[gi];
    float4 a = ((const float4*)anch)[gi];
    float aw = a.z - a.x, ah = a.w - a.y;
    float acx = a.x + 0.5f * aw, acy = a.y + 0.5f * ah;
    float rx = opaquef(r.x * 0.1f), ry = opaquef(r.y * 0.1f);
    float rw = opaquef(r.z * 0.2f), rh = opaquef(r.w * 0.2f);
    float pw = opaquef((float)exp((double)rw) * aw);
    float ph = opaquef((float)exp((double)rh) * ah);
    float pcx = opaquef(rx * aw) + acx;
    float pcy = opaquef(ry * ah) + acy;
    float x1 = truncf(pcx - 0.5f * pw);
    float y1 = truncf(pcy - 0.5f * ph);
    float x2 = truncf(pcx + 0.5f * pw);
    float y2 = truncf(pcy + 0.5f * ph);
    x1 = fmaxf(x1, 0.0f); y1 = fmaxf(y1, 0.0f);
    x2 = fminf(x2, 639.0f); y2 = fminf(y2, 639.0f);

    tsc[img * 1024 + tid] = score;
    tcl[img * 1024 + tid] = ci;
    ((float4*)tbox)[img * 1024 + tid] = make_float4(x1, y1, x2, y2);
}

// ---------------------------------------------------------------------------
// Phase E: greedy NMS, one 1024-thread block per image. Each iteration selects
// the next surviving candidate (bit scan of 16 alive words) and computes its
// 1000 IoUs on the fly (1 per thread) — suppressed candidates cost nothing.
// Boxes are small integers -> IoU math exact. Early exit at 100 keeps.
// ---------------------------------------------------------------------------
__global__ __launch_bounds__(1024) void nms_kernel(const float* __restrict__ tsc,
                                                   const int* __restrict__ tcl,
                                                   const float* __restrict__ tbox,
                                                   float* __restrict__ out) {
    const int img = blockIdx.x, tid = threadIdx.x;
    const int wave = tid >> 6, lane = tid & 63;
    __shared__ float4 sb[1000];
    __shared__ float sa[1000];
    __shared__ float ssc[1000];
    __shared__ u64 alive[16];
    __shared__ int s_cur, s_kept;
    __shared__ int keeplist[MAXDET];

    bool v = false;
    float4 b = make_float4(0, 0, 0, 0);
    float myarea = 0.0f;
    if (tid < 1000) {
        b = ((const float4*)tbox)[img * 1024 + tid];
        myarea = (b.z - b.x) * (b.w - b.y);
        sb[tid] = b; sa[tid] = myarea;
        float sc = tsc[img * 1024 + tid];
        ssc[tid] = sc;
        v = sc > 0.05f;
    }
    u64 bal = __ballot(v);
    if (lane == 0) alive[wave] = bal;
    if (tid == 0) s_kept = 0;
    __syncthreads();

    for (;;) {
        if (tid == 0) {
            int i = -1;
#pragma unroll
            for (int w = 0; w < 16; ++w) {
                u64 aw = alive[w];
                if (aw) { int bt = __builtin_ctzll(aw); i = w * 64 + bt; alive[w] = aw & (aw - 1); break; }
            }
            if (i >= 0) { keeplist[s_kept] = i; s_kept = s_kept + 1; }
            s_cur = i;
        }
        __syncthreads();
        int i = s_cur;
        if (i < 0 || s_kept >= MAXDET) break;
        bool sup = false;
        if (tid < 1000 && tid > i) {
            float4 bi = sb[i];
            float ai = sa[i];
            float ltx = fmaxf(bi.x, b.x), lty = fmaxf(bi.y, b.y);
            float rbx = fminf(bi.z, b.z), rby = fminf(bi.w, b.w);
            float dx = fmaxf(rbx - ltx, 0.0f), dy = fmaxf(rby - lty, 0.0f);
            float inter = dx * dy;                 // exact int
            float uni = ai + myarea - inter;       // exact int
            sup = (inter / uni) > 0.5f;            // IEEE div, bit-exact vs numpy
        }
        u64 m = __ballot(sup);
        if (lane == 0) alive[wave] &= ~m;
        __syncthreads();
    }

    const int n = s_kept;
    if (tid < MAXDET) {
        int o = img * MAXDET + tid;
        if (tid < n) {
            int i = keeplist[tid];
            out[o] = ssc[i];
            out[NB * MAXDET + o] = (float)tcl[img * 1024 + i];
            ((float4*)(out + 2 * NB * MAXDET))[o] = sb[i];
        } else {
            out[o] = -1.0f;
            out[NB * MAXDET + o] = -1.0f;
            ((float4*)(out + 2 * NB * MAXDET))[o] = make_float4(-1.0f, -1.0f, -1.0f, -1.0f);
        }
    }
}

// ---------------------------------------------------------------------------
extern "C" void kernel_launch(void* const* d_in, const int* in_sizes, int n_in,
                              void* d_out, int out_size, void* d_ws, size_t ws_size,
                              hipStream_t stream) {
    const float* cls  = (const float*)d_in[0];
    const float* reg  = (const float*)d_in[1];
    const float* anch = (const float*)d_in[2];
    float* out = (float*)d_out;

    // workspace layout (~8.5 MB)
    u32* ctrl = (u32*)d_ws;                                   // ZWORDS u32, zeroed by score_kernel
    u64* keys = (u64*)((char*)d_ws + (size_t)ZWORDS * 4);     // NB*AN u64 (offset 525312, 8B-aligned)
    u64* topk = keys + (size_t)NB * AN;                       // NB*1024 u64
    float* tsc = (float*)(topk + NB * 1024);                  // NB*1024 f32
    int*   tcl = (int*)(tsc + NB * 1024);                     // NB*1024 i32
    float* tbox = (float*)(tcl + NB * 1024);                  // NB*1024*4 f32 (16B-aligned)

    score_kernel<<<dim3(3750), dim3(256), 0, stream>>>(cls, keys, ctrl);
    hist_kernel<0><<<dim3(480), dim3(256), 0, stream>>>(keys, ctrl);
    hist_kernel<1><<<dim3(480), dim3(256), 0, stream>>>(keys, ctrl);
    hist_kernel<2><<<dim3(480), dim3(256), 0, stream>>>(keys, ctrl);
    hist_kernel<3><<<dim3(480), dim3(256), 0, stream>>>(keys, ctrl);
    compact_kernel<<<dim3(480), dim3(256), 0, stream>>>(keys, ctrl, topk);
    sortdecode_kernel<<<dim3(NB), dim3(1024), 0, stream>>>(topk, ctrl, cls, reg, anch, tsc, tcl, tbox);
    nms_kernel<<<dim3(NB), dim3(1024), 0, stream>>>(tsc, tcl, tbox, out);
}